// Round 21
// baseline (1036.376 us; speedup 1.0000x reference)
//
#include <hip/hip_runtime.h>
#include <stdint.h>

typedef _Float16 f16;
typedef __attribute__((ext_vector_type(8))) _Float16 f16x8;
typedef __attribute__((ext_vector_type(4))) _Float16 f16x4;
typedef __attribute__((ext_vector_type(4))) float f32x4;

constexpr int kT = 4096;    // B*L tokens
constexpr int kD = 1024;    // hidden
constexpr int kDW = 512;    // word embed proj dim
constexpr int kF = 4096;    // ffn
constexpr int kV = 50272;   // vocab

// Async global->LDS: HW places lane i's 16B at lds_base + i*16 (wave-uniform base).
__device__ __forceinline__ void gload16(const void* g, void* lbase, int lane) {
#if __has_builtin(__builtin_amdgcn_global_load_lds)
  __builtin_amdgcn_global_load_lds((const __attribute__((address_space(1))) void*)g,
                                   (__attribute__((address_space(3))) void*)lbase, 16, 0, 0);
#else
  *(f16x8*)((char*)lbase + lane * 16) = *(const f16x8*)g;
#endif
}

// ---------------------------------------------------------------------------
// gemm_p8 (proven best): 128x128 tile, 512 threads (8 waves), BK=64
// double-buffered LDS (64 KB -> 2 blocks/CU), counted vmcnt(4), row&7-XOR
// bank swizzle via pre-swizzled global source, XCD chunk swizzle.
// Split-K S. flags: bit0 relu (S==1), bit1 f32 out, bit2 f16 split partial
// ((f16*)Cv + s*M*ldc; bias on split 0 only).
// ---------------------------------------------------------------------------
__global__ __launch_bounds__(512, 4) void gemm_p8(
    const f16* __restrict__ A, const f16* __restrict__ W,
    const float* __restrict__ bias, void* __restrict__ Cv,
    int M, int N, int K, int ldc, int flags, int S)
{
  __shared__ f16 LA[2][128 * 64];
  __shared__ f16 LB[2][128 * 64];
  const int tid = threadIdx.x, lane = tid & 63, wv = tid >> 6;
  const int nby = M >> 7;
  const int nb = nby * (N >> 7);
  int id = blockIdx.x;
  id = (id & 7) * ((int)gridDim.x >> 3) + (id >> 3);   // XCD chunk swizzle
  const int s = id / nb;
  const int r = id - s * nb;
  const int bx = r / nby, by = r - bx * nby;
  const int row0 = by * 128, col0 = bx * 128;
  const int klen = K / S, koff = s * klen;
  const int wm = (wv >> 1) * 32, wn = (wv & 1) * 64;
  const int l15 = lane & 15, l4 = lane >> 4;

  f32x4 acc[2][4] = {};

  const int srow = wv * 16 + (lane >> 3);
  const int schunk = ((lane & 7) ^ (lane >> 3)) * 8;    // f16 units
  const f16* Ag = A + (size_t)(row0 + srow) * K + koff + schunk;
  const f16* Wg = W + (size_t)(col0 + srow) * K + koff + schunk;
  const int lrow = wv * 16;

  const int nt = klen >> 6;
#pragma unroll
  for (int j = 0; j < 2; ++j) {
    gload16(Ag + (size_t)j * 8 * K, &LA[0][(lrow + j * 8) * 64], lane);
    gload16(Wg + (size_t)j * 8 * K, &LB[0][(lrow + j * 8) * 64], lane);
  }

  for (int t = 0; t < nt; ++t) {
    const int cur = t & 1;
    if (t + 1 < nt) {
      const size_t ko = (size_t)(t + 1) * 64;
#pragma unroll
      for (int j = 0; j < 2; ++j) {
        gload16(Ag + (size_t)j * 8 * K + ko, &LA[cur ^ 1][(lrow + j * 8) * 64], lane);
        gload16(Wg + (size_t)j * 8 * K + ko, &LB[cur ^ 1][(lrow + j * 8) * 64], lane);
      }
      asm volatile("s_waitcnt vmcnt(4)" ::: "memory");   // stage(t) done; stage(t+1) in flight
    } else {
      asm volatile("s_waitcnt vmcnt(0)" ::: "memory");
    }
    __builtin_amdgcn_s_barrier();

    f16x8 af[2][2], bf[2][4];
#pragma unroll
    for (int ks = 0; ks < 2; ++ks) {
#pragma unroll
      for (int mr = 0; mr < 2; ++mr) {
        const int rowa = wm + mr * 16 + l15;
        af[ks][mr] = *(const f16x8*)&LA[cur][rowa * 64 + (((ks * 4 + l4) ^ (rowa & 7)) * 8)];
      }
#pragma unroll
      for (int nr = 0; nr < 4; ++nr) {
        const int rowb = wn + nr * 16 + l15;
        bf[ks][nr] = *(const f16x8*)&LB[cur][rowb * 64 + (((ks * 4 + l4) ^ (rowb & 7)) * 8)];
      }
    }
#pragma unroll
    for (int mr = 0; mr < 2; ++mr)
#pragma unroll
      for (int nr = 0; nr < 4; ++nr) {
        acc[mr][nr] = __builtin_amdgcn_mfma_f32_16x16x32_f16(af[0][mr], bf[0][nr], acc[mr][nr], 0, 0, 0);
        acc[mr][nr] = __builtin_amdgcn_mfma_f32_16x16x32_f16(af[1][mr], bf[1][nr], acc[mr][nr], 0, 0, 0);
      }
    __builtin_amdgcn_sched_barrier(0);
    __builtin_amdgcn_s_barrier();
  }

  const bool relu = (flags & 1) != 0;
  const bool outf = (flags & 2) != 0;
  const bool ph16 = (flags & 4) != 0;
  float* Cf = (float*)Cv + (size_t)s * M * ldc;
  f16* Cp = (f16*)Cv + (size_t)s * M * ldc;
  f16* Ch = (f16*)Cv;
  const float* bs = (s == 0) ? bias : nullptr;
#pragma unroll
  for (int nr = 0; nr < 4; ++nr) {
    const int col = col0 + wn + nr * 16 + l15;
    const float bv = bs ? bs[col] : 0.f;
#pragma unroll
    for (int mr = 0; mr < 2; ++mr) {
#pragma unroll
      for (int rr = 0; rr < 4; ++rr) {
        const int row = row0 + wm + mr * 16 + l4 * 4 + rr;
        float v = acc[mr][nr][rr] + bv;
        if (relu) v = fmaxf(v, 0.f);
        if (ph16)      Cp[(size_t)row * ldc + col] = (f16)v;
        else if (outf) Cf[(size_t)row * ldc + col] = v;
        else           Ch[(size_t)row * ldc + col] = (f16)v;
      }
    }
  }
}

// ---------------------------------------------------------------------------
// Fallback GEMM (W in f32, converted through regs) — round-0 proven kernel.
// ---------------------------------------------------------------------------
__global__ __launch_bounds__(256) void gemm_f16(
    const f16* __restrict__ A, const float* __restrict__ W,
    const float* __restrict__ bias, void* __restrict__ Cv,
    int M, int N, int K, int ldc, int flags)
{
  __shared__ f16 As[128][40];
  __shared__ f16 Ws[128][40];
  const int tid = threadIdx.x;
  const int lane = tid & 63;
  const int wid = tid >> 6;
  const int row0 = blockIdx.y * 128, col0 = blockIdx.x * 128;
  const int wm = (wid >> 1) * 64, wn = (wid & 1) * 64;
  const int l15 = lane & 15, k8 = (lane >> 4) * 8;
  const int lr = tid >> 2, lc8 = (tid & 3) * 8;

  f32x4 acc[4][4] = {};

  const f16* Ap = A + (size_t)(row0 + lr) * K + lc8;
  const float* Wp = W + (size_t)(col0 + lr) * K + lc8;

  for (int k0 = 0; k0 < K; k0 += 32) {
    f16x8 a0 = *(const f16x8*)(Ap + k0);
    f16x8 a1 = *(const f16x8*)(Ap + (size_t)64 * K + k0);
    f32x4 w00 = *(const f32x4*)(Wp + k0);
    f32x4 w01 = *(const f32x4*)(Wp + k0 + 4);
    f32x4 w10 = *(const f32x4*)(Wp + (size_t)64 * K + k0);
    f32x4 w11 = *(const f32x4*)(Wp + (size_t)64 * K + k0 + 4);
    f16x8 wv0, wv1;
#pragma unroll
    for (int j = 0; j < 4; ++j) {
      wv0[j] = (f16)w00[j]; wv0[4 + j] = (f16)w01[j];
      wv1[j] = (f16)w10[j]; wv1[4 + j] = (f16)w11[j];
    }
    __syncthreads();
    *(f16x8*)&As[lr][lc8] = a0;
    *(f16x8*)&As[lr + 64][lc8] = a1;
    *(f16x8*)&Ws[lr][lc8] = wv0;
    *(f16x8*)&Ws[lr + 64][lc8] = wv1;
    __syncthreads();
    f16x8 af[4], bfr[4];
#pragma unroll
    for (int r = 0; r < 4; ++r) af[r] = *(const f16x8*)&As[wm + r * 16 + l15][k8];
#pragma unroll
    for (int r = 0; r < 4; ++r) bfr[r] = *(const f16x8*)&Ws[wn + r * 16 + l15][k8];
#pragma unroll
    for (int mr = 0; mr < 4; ++mr)
#pragma unroll
      for (int nr = 0; nr < 4; ++nr)
        acc[mr][nr] = __builtin_amdgcn_mfma_f32_16x16x32_f16(af[mr], bfr[nr], acc[mr][nr], 0, 0, 0);
  }

  const bool relu = (flags & 1) != 0;
  const bool outf = (flags & 2) != 0;
  float* Cf = (float*)Cv;
  f16* Ch = (f16*)Cv;
#pragma unroll
  for (int nr = 0; nr < 4; ++nr) {
    const int col = col0 + wn + nr * 16 + l15;
    const float bv = bias ? bias[col] : 0.f;
#pragma unroll
    for (int mr = 0; mr < 4; ++mr) {
#pragma unroll
      for (int r = 0; r < 4; ++r) {
        const int row = row0 + wm + mr * 16 + (lane >> 4) * 4 + r;
        float v = acc[mr][nr][r] + bv;
        if (relu) v = fmaxf(v, 0.f);
        if (outf) Cf[(size_t)row * ldc + col] = v;
        else      Ch[(size_t)row * ldc + col] = (f16)v;
      }
    }
  }
}

// ---------------------------------------------------------------------------
// MFMA causal flash attention v4 + T5 setprio (neutral but harmless).
// Fixed-offset softmax P = exp2(S*0.125*log2e - 8*log2e); masked -> 0;
// lane-local l accumulation; K/V tile t+1 prefetched into registers.
// grid (L/128, H, B), 256 threads = 4 waves.
// ---------------------------------------------------------------------------
__global__ __launch_bounds__(256) void attn_mfma4(const f16* __restrict__ qkv,
                                                  f16* __restrict__ out)
{
  __shared__ f16 Ks[64][72];
  __shared__ f16 Vt[64][72];
  __shared__ f16 Ps[4][32][72];
  const int qt = blockIdx.x, h = blockIdx.y, b = blockIdx.z;
  const int tid = threadIdx.x, lane = tid & 63, wv = tid >> 6;
  const int l15 = lane & 15, l4 = lane >> 4;
  constexpr float kC1 = 0.18033688f;    // 0.125 * log2(e)
  constexpr float kC2 = -11.5415603f;   // -8 * log2(e)

  f16x8 qa[2][2];
#pragma unroll
  for (int mr = 0; mr < 2; ++mr) {
    const size_t qrow = (size_t)(b * 1024 + qt * 128 + wv * 32 + mr * 16 + l15);
#pragma unroll
    for (int ks = 0; ks < 2; ++ks)
      qa[mr][ks] = *(const f16x8*)(qkv + qrow * 3072 + h * 64 + ks * 32 + l4 * 8);
  }

  float l[2][4] = {};
  f32x4 o[2][4] = {};

  const int skey = tid >> 2;
  const int spart = (tid & 3) * 16;
  const int vxor = (skey >> 3) ^ (tid & 3);
  const int vcol = vxor * 8 + (skey & 7);
  const int qmin = qt * 128 + wv * 32;
  const int ntiles = 2 * qt + 2;

  f16x8 kk0, kk1, vv0, vv1;
  {
    const f16* kvb = qkv + (size_t)(b * 1024 + skey) * 3072 + h * 64;
    kk0 = *(const f16x8*)(kvb + 1024 + spart);
    kk1 = *(const f16x8*)(kvb + 1024 + spart + 8);
    vv0 = *(const f16x8*)(kvb + 2048 + spart);
    vv1 = *(const f16x8*)(kvb + 2048 + spart + 8);
  }

  for (int kt = 0; kt < ntiles; ++kt) {
    *(f16x8*)&Ks[skey][spart] = kk0;
    *(f16x8*)&Ks[skey][spart + 8] = kk1;
#pragma unroll
    for (int j = 0; j < 8; ++j) {
      Vt[spart + j][vcol] = vv0[j];
      Vt[spart + 8 + j][vcol] = vv1[j];
    }
    __syncthreads();
    if (kt + 1 < ntiles) {
      const f16* kvb = qkv + (size_t)(b * 1024 + (kt + 1) * 64 + skey) * 3072 + h * 64;
      kk0 = *(const f16x8*)(kvb + 1024 + spart);
      kk1 = *(const f16x8*)(kvb + 1024 + spart + 8);
      vv0 = *(const f16x8*)(kvb + 2048 + spart);
      vv1 = *(const f16x8*)(kvb + 2048 + spart + 8);
    }

    if (kt * 64 <= qmin + 31) {
      f32x4 s[2][4] = {};
      __builtin_amdgcn_s_setprio(1);
#pragma unroll
      for (int f = 0; f < 4; ++f) {
        f16x8 kb0 = *(const f16x8*)&Ks[f * 16 + l15][l4 * 8];
        f16x8 kb1 = *(const f16x8*)&Ks[f * 16 + l15][32 + l4 * 8];
#pragma unroll
        for (int mr = 0; mr < 2; ++mr) {
          s[mr][f] = __builtin_amdgcn_mfma_f32_16x16x32_f16(qa[mr][0], kb0, s[mr][f], 0, 0, 0);
          s[mr][f] = __builtin_amdgcn_mfma_f32_16x16x32_f16(qa[mr][1], kb1, s[mr][f], 0, 0, 0);
        }
      }
      __builtin_amdgcn_s_setprio(0);
#pragma unroll
      for (int mr = 0; mr < 2; ++mr) {
        float sc[4][4];
        const bool needmask = (kt * 64 + 63) > (qmin + mr * 16);
        if (needmask) {
#pragma unroll
          for (int f = 0; f < 4; ++f)
#pragma unroll
            for (int r = 0; r < 4; ++r) {
              const int qg = qmin + mr * 16 + l4 * 4 + r;
              const int kg = kt * 64 + f * 16 + l15;
              sc[f][r] = (kg <= qg) ? exp2f(fmaf(s[mr][f][r], kC1, kC2)) : 0.f;
            }
        } else {
#pragma unroll
          for (int f = 0; f < 4; ++f)
#pragma unroll
            for (int r = 0; r < 4; ++r)
              sc[f][r] = exp2f(fmaf(s[mr][f][r], kC1, kC2));
        }
#pragma unroll
        for (int r = 0; r < 4; ++r)
          l[mr][r] += (sc[0][r] + sc[1][r]) + (sc[2][r] + sc[3][r]);
#pragma unroll
        for (int f = 0; f < 4; ++f)
#pragma unroll
          for (int r = 0; r < 4; ++r)
            Ps[wv][mr * 16 + l4 * 4 + r][f * 16 + l15] = (f16)sc[f][r];
      }
      f16x8 pa[2][2];
#pragma unroll
      for (int mr = 0; mr < 2; ++mr)
#pragma unroll
        for (int ks = 0; ks < 2; ++ks)
          pa[mr][ks] = *(const f16x8*)&Ps[wv][mr * 16 + l15][ks * 32 + l4 * 8];
      __builtin_amdgcn_s_setprio(1);
#pragma unroll
      for (int hf = 0; hf < 4; ++hf) {
        f16x8 vb0 = *(const f16x8*)&Vt[hf * 16 + l15][((l4) ^ hf) * 8];
        f16x8 vb1 = *(const f16x8*)&Vt[hf * 16 + l15][((4 + l4) ^ hf) * 8];
#pragma unroll
        for (int mr = 0; mr < 2; ++mr) {
          o[mr][hf] = __builtin_amdgcn_mfma_f32_16x16x32_f16(pa[mr][0], vb0, o[mr][hf], 0, 0, 0);
          o[mr][hf] = __builtin_amdgcn_mfma_f32_16x16x32_f16(pa[mr][1], vb1, o[mr][hf], 0, 0, 0);
        }
      }
      __builtin_amdgcn_s_setprio(0);
    }
    __syncthreads();
  }

#pragma unroll
  for (int mr = 0; mr < 2; ++mr) {
    float inv[4];
#pragma unroll
    for (int r = 0; r < 4; ++r) {
      float L = l[mr][r];
      L += __shfl_xor(L, 1);
      L += __shfl_xor(L, 2);
      L += __shfl_xor(L, 4);
      L += __shfl_xor(L, 8);
      inv[r] = 1.f / L;
    }
    f16* dst = out + (size_t)(b * 1024 + qt * 128 + wv * 32 + mr * 16 + l4 * 4) * 1024 + h * 64 + l15;
#pragma unroll
    for (int hf = 0; hf < 4; ++hf)
#pragma unroll
      for (int r = 0; r < 4; ++r)
        dst[(size_t)r * 1024 + hf * 16] = (f16)(o[mr][hf][r] * inv[r]);
  }
}

// ---------------------------------------------------------------------------
// LayerNorm, pure-f16 residual stream: out_h = f16(LN(v) * w + b).
// ---------------------------------------------------------------------------
__device__ __forceinline__ void ln_body_h(f32x4 v, const float* w, const float* bvec,
                                          f16* Oh, size_t base, int tid)
{
  float sm = v[0] + v[1] + v[2] + v[3];
  float sq = v[0] * v[0] + v[1] * v[1] + v[2] * v[2] + v[3] * v[3];
#pragma unroll
  for (int msk = 32; msk; msk >>= 1) { sm += __shfl_xor(sm, msk); sq += __shfl_xor(sq, msk); }
  __shared__ float sb[4], qb_[4];
  const int wid = tid >> 6, lane = tid & 63;
  if (lane == 0) { sb[wid] = sm; qb_[wid] = sq; }
  __syncthreads();
  sm = sb[0] + sb[1] + sb[2] + sb[3];
  sq = qb_[0] + qb_[1] + qb_[2] + qb_[3];
  const float mean = sm * (1.f / 1024.f);
  const float var = sq * (1.f / 1024.f) - mean * mean;
  const float rstd = rsqrtf(var + 1e-5f);
  const f32x4 w4 = *(const f32x4*)&w[tid * 4];
  const f32x4 b4 = *(const f32x4*)&bvec[tid * 4];
  f16x4 yh;
#pragma unroll
  for (int j = 0; j < 4; ++j)
    yh[j] = (f16)((v[j] - mean) * rstd * w4[j] + b4[j]);
  *(f16x4*)&Oh[base] = yh;
}

// out_h = LN(R_h + X1h + X2h); in-place safe (one row per block).
__global__ __launch_bounds__(256) void add_lnh(
    const f16* __restrict__ R, const f16* __restrict__ X1,
    const f16* __restrict__ X2,
    const float* __restrict__ w, const float* __restrict__ bvec,
    f16* __restrict__ Oh)
{
  const int row = blockIdx.x, tid = threadIdx.x;
  const size_t base = (size_t)row * 1024 + tid * 4;
  const f16x4 r4 = *(const f16x4*)&R[base];
  const f16x4 x1 = *(const f16x4*)&X1[base];
  const f16x4 x2 = *(const f16x4*)&X2[base];
  f32x4 v;
#pragma unroll
  for (int j = 0; j < 4; ++j) v[j] = (float)r4[j] + (float)x1[j] + (float)x2[j];
  ln_body_h(v, w, bvec, Oh, base, tid);
}

// legacy 2-input f32 version (fallback path)
__global__ __launch_bounds__(256) void add_ln(
    const float* __restrict__ R, const float* __restrict__ X,
    const float* __restrict__ w, const float* __restrict__ bvec,
    float* __restrict__ O32, f16* __restrict__ Oh)
{
  const int row = blockIdx.x, tid = threadIdx.x;
  const size_t base = (size_t)row * 1024 + tid * 4;
  f32x4 v = *(const f32x4*)&R[base];
  v += *(const f32x4*)&X[base];
  float sm = v[0] + v[1] + v[2] + v[3];
  float sq = v[0] * v[0] + v[1] * v[1] + v[2] * v[2] + v[3] * v[3];
#pragma unroll
  for (int msk = 32; msk; msk >>= 1) { sm += __shfl_xor(sm, msk); sq += __shfl_xor(sq, msk); }
  __shared__ float sb[4], qb_[4];
  const int wid = tid >> 6, lane = tid & 63;
  if (lane == 0) { sb[wid] = sm; qb_[wid] = sq; }
  __syncthreads();
  sm = sb[0] + sb[1] + sb[2] + sb[3];
  sq = qb_[0] + qb_[1] + qb_[2] + qb_[3];
  const float mean = sm * (1.f / 1024.f);
  const float var = sq * (1.f / 1024.f) - mean * mean;
  const float rstd = rsqrtf(var + 1e-5f);
  const f32x4 w4 = *(const f32x4*)&w[tid * 4];
  const f32x4 b4 = *(const f32x4*)&bvec[tid * 4];
  f32x4 y;
  f16x4 yh;
#pragma unroll
  for (int j = 0; j < 4; ++j) {
    y[j] = (v[j] - mean) * rstd * w4[j] + b4[j];
    yh[j] = (f16)y[j];
  }
  *(f32x4*)&O32[base] = y;
  *(f16x4*)&Oh[base] = yh;
}

// E[t, :] = f16(embed_w[ids[t], :])   (fallback path)
__global__ __launch_bounds__(256) void gather_embed(
    const int* __restrict__ ids, const float* __restrict__ ew, f16* __restrict__ E)
{
  const int idx = blockIdx.x * 256 + threadIdx.x;
  const int t = idx >> 6, c = (idx & 63) * 8;
  const float* src = ew + (size_t)ids[t] * 512 + c;
  f32x4 f0 = *(const f32x4*)src, f1 = *(const f32x4*)(src + 4);
  f16x8 o_;
#pragma unroll
  for (int j = 0; j < 4; ++j) { o_[j] = (f16)f0[j]; o_[4 + j] = (f16)f1[j]; }
  *(f16x8*)(E + (size_t)t * 512 + c) = o_;
}

// Hh = f16(X1h + X2h + pos_w[positions[t]+2])
__global__ __launch_bounds__(256) void pos_addh(
    const f16* __restrict__ X1, const f16* __restrict__ X2,
    const float* __restrict__ posw,
    const int* __restrict__ positions, f16* __restrict__ Hh)
{
  const int idx = blockIdx.x * 256 + threadIdx.x;
  const int t = idx >> 7, c = (idx & 127) * 8;
  const size_t base = (size_t)t * 1024 + c;
  const float* pp = posw + (size_t)(positions[t] + 2) * 1024 + c;
  const f16x8 x1 = *(const f16x8*)&X1[base];
  const f16x8 x2 = *(const f16x8*)&X2[base];
  f32x4 a0 = *(const f32x4*)pp;
  f32x4 a1 = *(const f32x4*)(pp + 4);
  f16x8 hh;
#pragma unroll
  for (int j = 0; j < 4; ++j) {
    hh[j]     = (f16)(a0[j] + (float)x1[j] + (float)x2[j]);
    hh[4 + j] = (f16)(a1[j] + (float)x1[4 + j] + (float)x2[4 + j]);
  }
  *(f16x8*)&Hh[base] = hh;
}

// legacy single-input version (fallback path)
__global__ __launch_bounds__(256) void pos_add(
    const float* __restrict__ X, const float* __restrict__ posw,
    const int* __restrict__ positions, float* __restrict__ H32, f16* __restrict__ Hh)
{
  const int idx = blockIdx.x * 256 + threadIdx.x;
  const int t = idx >> 7, c = (idx & 127) * 8;
  const float* xp = X + (size_t)t * 1024 + c;
  const float* pp = posw + (size_t)(positions[t] + 2) * 1024 + c;
  f32x4 a0 = *(const f32x4*)xp, a1 = *(const f32x4*)(xp + 4);
  a0 += *(const f32x4*)pp;
  a1 += *(const f32x4*)(pp + 4);
  f16x8 hh;
#pragma unroll
  for (int j = 0; j < 4; ++j) { hh[j] = (f16)a0[j]; hh[4 + j] = (f16)a1[j]; }
  *(f32x4*)&H32[(size_t)t * 1024 + c] = a0;
  *(f32x4*)&H32[(size_t)t * 1024 + c + 4] = a1;
  *(f16x8*)&Hh[(size_t)t * 1024 + c] = hh;
}

// y[b, w] = hbf[offsets[b]-1, :] . proj_out_w[w, :]   (one wave per output)
__global__ __launch_bounds__(256) void last_projh(
    const f16* __restrict__ Hh, const float* __restrict__ pw,
    const int* __restrict__ offs, float* __restrict__ y)
{
  const int o = blockIdx.x * 4 + (threadIdx.x >> 6), lane = threadIdx.x & 63;
  const int b = o >> 9, w = o & 511;
  const int row = offs[b] - 1;
  const f16* hp = Hh + (size_t)row * 1024 + lane * 16;
  const float* wp = pw + (size_t)w * 1024 + lane * 16;
  const f16x8 h0 = *(const f16x8*)hp;
  const f16x8 h1 = *(const f16x8*)(hp + 8);
  float s = 0.f;
#pragma unroll
  for (int j = 0; j < 8; ++j) {
    s += (float)h0[j] * wp[j];
    s += (float)h1[j] * wp[8 + j];
  }
#pragma unroll
  for (int msk = 32; msk; msk >>= 1) s += __shfl_xor(s, msk);
  if (lane == 0) y[o] = s;
}

// legacy f32 version (fallback path)
__global__ __launch_bounds__(256) void last_proj(
    const float* __restrict__ H32, const float* __restrict__ pw,
    const int* __restrict__ offs, float* __restrict__ y)
{
  const int o = blockIdx.x * 4 + (threadIdx.x >> 6), lane = threadIdx.x & 63;
  const int b = o >> 9, w = o & 511;
  const int row = offs[b] - 1;
  const float* hp = H32 + (size_t)row * 1024;
  const float* wp = pw + (size_t)w * 1024;
  float s = 0.f;
#pragma unroll
  for (int j = 0; j < 4; ++j) {
    f32x4 hv = *(const f32x4*)&hp[(lane + 64 * j) * 4];
    f32x4 wv = *(const f32x4*)&wp[(lane + 64 * j) * 4];
    s += hv[0] * wv[0] + hv[1] * wv[1] + hv[2] * wv[2] + hv[3] * wv[3];
  }
#pragma unroll
  for (int msk = 32; msk; msk >>= 1) s += __shfl_xor(s, msk);
  if (lane == 0) y[o] = s;
}

// logits: each block = 4 vocab rows x all 4 batches (embed read once).
__global__ __launch_bounds__(256) void logits4(const float* __restrict__ y,
                                               const float* __restrict__ ew,
                                               float* __restrict__ out)
{
  __shared__ float ys[2048];
  const int tid = threadIdx.x;
  ((f32x4*)ys)[tid] = ((const f32x4*)y)[tid];
  ((f32x4*)ys)[tid + 256] = ((const f32x4*)y)[tid + 256];
  __syncthreads();
  const int v = blockIdx.x * 4 + (tid >> 6);
  const int lane = tid & 63;
  const float* wp = ew + (size_t)v * 512 + lane * 8;
  const f32x4 e0 = *(const f32x4*)wp;
  const f32x4 e1 = *(const f32x4*)(wp + 4);
  float s0 = 0.f, s1 = 0.f, s2 = 0.f, s3 = 0.f;
#pragma unroll
  for (int j = 0; j < 4; ++j) {
    const int c0 = lane * 8 + j, c1 = lane * 8 + 4 + j;
    s0 += e0[j] * ys[c0] + e1[j] * ys[c1];
    s1 += e0[j] * ys[512 + c0] + e1[j] * ys[512 + c1];
    s2 += e0[j] * ys[1024 + c0] + e1[j] * ys[1024 + c1];
    s3 += e0[j] * ys[1536 + c0] + e1[j] * ys[1536 + c1];
  }
#pragma unroll
  for (int msk = 32; msk; msk >>= 1) {
    s0 += __shfl_xor(s0, msk); s1 += __shfl_xor(s1, msk);
    s2 += __shfl_xor(s2, msk); s3 += __shfl_xor(s3, msk);
  }
  if (lane == 0) {
    out[v] = s0;
    out[50272 + v] = s1;
    out[2 * 50272 + v] = s2;
    out[3 * 50272 + v] = s3;
  }
}

// ---------------------------------------------------------------------------
// pack_all: single-launch prep, GRID-STRIDE at 2048 blocks (G11: avoid tiny
// block churn; each thread handles ~13 items). Flat index space, range
// dispatch; per-item mappings byte-identical to r20 (which validated).
// Segments (f16x8 work items unless noted):
//   [0,          65536)   proj_in_w  -> pw_in
//   [65536,    1638400)   q|k|v pack -> qkvw
//   [1638400,  2162688)   ow         -> oww
//   [2162688,  4259840)   fc1w       -> f1w
//   [4259840,  6356992)   fc2w       -> f2w
//   [6356992,  6619136)   embed gather -> E   (T*64 = 262144 items)
//   [6619136,  6631424)   qkv bias scalars -> qkvb (1 f32/item)
// ---------------------------------------------------------------------------
__global__ __launch_bounds__(256) void pack_all(
    const float* __restrict__ proj_in_w, f16* __restrict__ pw_in,
    const float* __restrict__ qw, const float* __restrict__ kw,
    const float* __restrict__ vw, f16* __restrict__ qkvw,
    const float* __restrict__ ow, f16* __restrict__ oww,
    const float* __restrict__ fc1w, f16* __restrict__ f1w,
    const float* __restrict__ fc2w, f16* __restrict__ f2w,
    const int* __restrict__ ids, const float* __restrict__ ew, f16* __restrict__ E,
    const float* __restrict__ qb, const float* __restrict__ kb,
    const float* __restrict__ vb, float* __restrict__ qkvb)
{
  const int stride = (int)gridDim.x * 256;
  for (int idx = blockIdx.x * 256 + threadIdx.x; idx < 6631424; idx += stride) {
    const float* src = nullptr;
    f16* dst = nullptr;
    if (idx < 65536) {
      src = proj_in_w + (size_t)idx * 8;
      dst = pw_in + (size_t)idx * 8;
    } else if (idx < 1638400) {
      const size_t e = (size_t)(idx - 65536) * 8;
      const size_t li = e / 3145728;
      const size_t r = e - li * 3145728;
      const int mt = (int)(r >> 20);
      const size_t c = r & 1048575;
      src = (mt == 0 ? qw : (mt == 1 ? kw : vw)) + li * 1048576 + c;
      dst = qkvw + e;
    } else if (idx < 2162688) {
      const size_t e = (size_t)(idx - 1638400) * 8;
      src = ow + e;
      dst = oww + e;
    } else if (idx < 4259840) {
      const size_t e = (size_t)(idx - 2162688) * 8;
      src = fc1w + e;
      dst = f1w + e;
    } else if (idx < 6356992) {
      const size_t e = (size_t)(idx - 4259840) * 8;
      src = fc2w + e;
      dst = f2w + e;
    } else if (idx < 6619136) {
      const int j = idx - 6356992;                 // T*64 gather units
      const int t = j >> 6, c = (j & 63) * 8;
      src = ew + (size_t)ids[t] * 512 + c;
      dst = E + (size_t)t * 512 + c;
    } else {
      const int i = idx - 6619136;                 // qkv bias scalar
      const int li = i / 3072;
      const int r = i - li * 3072;
      const int mt = r >> 10;
      const int c = r & 1023;
      const float* s = (mt == 0 ? qb : (mt == 1 ? kb : vb));
      qkvb[i] = s[li * 1024 + c];
      continue;
    }
    const f32x4 a = *(const f32x4*)src;
    const f32x4 b = *(const f32x4*)(src + 4);
    f16x8 o_;
#pragma unroll
    for (int j = 0; j < 4; ++j) { o_[j] = (f16)a[j]; o_[4 + j] = (f16)b[j]; }
    *(f16x8*)dst = o_;
  }
}

// ---------------------------------------------------------------------------
extern "C" void kernel_launch(void* const* d_in, const int* in_sizes, int n_in,
                              void* d_out, int out_size, void* d_ws, size_t ws_size,
                              hipStream_t stream)
{
  const int* ids        = (const int*)d_in[0];
  const int* positions  = (const int*)d_in[1];
  const int* offs       = (const int*)d_in[2];
  const float* embed_w    = (const float*)d_in[6];
  const float* pos_w      = (const float*)d_in[7];
  const float* proj_in_w  = (const float*)d_in[8];
  const float* proj_out_w = (const float*)d_in[9];
  const float* ln1w = (const float*)d_in[10];
  const float* ln1b = (const float*)d_in[11];
  const float* qw   = (const float*)d_in[12];
  const float* qb   = (const float*)d_in[13];
  const float* kw   = (const float*)d_in[14];
  const float* kb   = (const float*)d_in[15];
  const float* vw   = (const float*)d_in[16];
  const float* vb   = (const float*)d_in[17];
  const float* ow   = (const float*)d_in[18];
  const float* ob   = (const float*)d_in[19];
  const float* fc1w = (const float*)d_in[20];
  const float* fc1b = (const float*)d_in[21];
  const float* fc2w = (const float*)d_in[22];
  const float* fc2b = (const float*)d_in[23];
  const float* ln2w = (const float*)d_in[24];
  const float* ln2b = (const float*)d_in[25];

  char* ws = (char*)d_ws;
  size_t off = 0;
  auto take = [&](size_t bytes) -> char* {
    char* p = ws + off;
    off += (bytes + 255) & ~(size_t)255;
    return p;
  };
  f16*   E   = (f16*)  take((size_t)kT * kDW * 2);
  float* h32 = (float*)take((size_t)kT * kD * 4);      // fallback path only
  f16*   hbf = (f16*)  take((size_t)kT * kD * 2);      // f16 residual stream
  f16*   qkv = (f16*)  take((size_t)kT * 3072 * 2);
  f16*   att = (f16*)  take((size_t)kT * kD * 2);
  f16*   t1  = (f16*)  take((size_t)kT * kF * 2);
  float* t2  = (float*)take((size_t)kT * kD * 4 * 2);  // region reused for f16 partials
  float* yb  = (float*)take((size_t)4 * kDW * 4);
  f16*   pw_in = (f16*)take((size_t)kD * kDW * 2);
  f16*   qkvw  = (f16*)take((size_t)4 * 3072 * kD * 2);
  f16*   oww   = (f16*)take((size_t)4 * kD * kD * 2);
  f16*   f1w   = (f16*)take((size_t)4 * kF * kD * 2);
  f16*   f2w   = (f16*)take((size_t)4 * kD * kF * 2);
  float* qkvb  = (float*)take((size_t)4 * 3072 * 4);
  const bool wok = (off <= ws_size);
  f16* tp  = (f16*)t2;                       // split partial 0 (f16)
  f16* tpb = tp + (size_t)kT * kD;           // split partial 1 (f16)
  (void)in_sizes; (void)n_in; (void)out_size;

  const dim3 blk(256);
  const dim3 blk8(512);
  const dim3 gD(kD / 128, kT / 128);
  const dim3 gF(kF / 128, kT / 128);
  const dim3 gAtt(8, 16, 4);         // 128-row q tiles
  const int nbD   = (kD / 128) * (kT / 128);     // 256
  const int nbQKV = (3072 / 128) * (kT / 128);   // 768
  const int nbF   = (kF / 128) * (kT / 128);     // 1024

  if (wok) {
    pack_all<<<2048, blk, 0, stream>>>(proj_in_w, pw_in, qw, kw, vw, qkvw,
                                       ow, oww, fc1w, f1w, fc2w, f2w,
                                       ids, embed_w, E, qb, kb, vb, qkvb);
  } else {
    gather_embed<<<1024, blk, 0, stream>>>(ids, embed_w, E);
  }

  if (wok) {
    gemm_p8<<<nbD * 2, blk8, 0, stream>>>(E, pw_in, nullptr, tp, kT, kD, kDW, kD, 4, 2);
    pos_addh<<<2048, blk, 0, stream>>>(tp, tpb, pos_w, positions, hbf);
  } else {
    gemm_f16<<<gD, blk, 0, stream>>>(E, proj_in_w, nullptr, t2, kT, kD, kDW, kD, 2);
    pos_add<<<2048, blk, 0, stream>>>(t2, pos_w, positions, h32, hbf);
  }

  for (int n = 0; n < 4; ++n) {
    const size_t wo = (size_t)n * kD * kD;
    if (wok) {
      gemm_p8<<<nbQKV, blk8, 0, stream>>>(hbf, qkvw + (size_t)n * 3145728, qkvb + n * 3072,
                                          qkv, kT, 3072, kD, 3072, 0, 1);
      attn_mfma4<<<gAtt, blk, 0, stream>>>(qkv, att);
      gemm_p8<<<nbD * 2, blk8, 0, stream>>>(att, oww + wo, ob + n * kD, tp, kT, kD, kD, kD, 4, 2);
      add_lnh<<<kT, blk, 0, stream>>>(hbf, tp, tpb, ln1w + n * kD, ln1b + n * kD, hbf);
      gemm_p8<<<nbF, blk8, 0, stream>>>(hbf, f1w + (size_t)n * kF * kD, fc1b + n * kF, t1, kT, kF, kD, kF, 1, 1);
      gemm_p8<<<nbD * 2, blk8, 0, stream>>>(t1, f2w + (size_t)n * kD * kF, fc2b + n * kD, tp, kT, kD, kF, kD, 4, 2);
      add_lnh<<<kT, blk, 0, stream>>>(hbf, tp, tpb, ln2w + n * kD, ln2b + n * kD, hbf);
    } else {
      gemm_f16<<<gD, blk, 0, stream>>>(hbf, qw + wo, qb + n * kD, qkv + 0,    kT, kD, kD, 3072, 0);
      gemm_f16<<<gD, blk, 0, stream>>>(hbf, kw + wo, kb + n * kD, qkv + 1024, kT, kD, kD, 3072, 0);
      gemm_f16<<<gD, blk, 0, stream>>>(hbf, vw + wo, vb + n * kD, qkv + 2048, kT, kD, kD, 3072, 0);
      attn_mfma4<<<gAtt, blk, 0, stream>>>(qkv, att);
      gemm_f16<<<gD, blk, 0, stream>>>(att, ow + wo, ob + n * kD, t2, kT, kD, kD, kD, 2);
      add_ln<<<kT, blk, 0, stream>>>(h32, t2, ln1w + n * kD, ln1b + n * kD, h32, hbf);
      gemm_f16<<<gF, blk, 0, stream>>>(hbf, fc1w + (size_t)n * kF * kD, fc1b + n * kF, t1, kT, kF, kD, kF, 1);
      gemm_f16<<<gD, blk, 0, stream>>>(t1, fc2w + (size_t)n * kD * kF, fc2b + n * kD, t2, kT, kD, kF, kD, 2);
      add_ln<<<kT, blk, 0, stream>>>(h32, t2, ln2w + n * kD, ln2b + n * kD, h32, hbf);
    }
  }

  if (wok) last_projh<<<512, blk, 0, stream>>>(hbf, proj_out_w, offs, yb);
  else     last_proj<<<512, blk, 0, stream>>>(h32, proj_out_w, offs, yb);
  logits4<<<12568, blk, 0, stream>>>(yb, embed_w, (float*)d_out);
}

// Round 22
// 1002.318 us; speedup vs baseline: 1.0340x; 1.0340x over previous
//
#include <hip/hip_runtime.h>
#include <stdint.h>

typedef _Float16 f16;
typedef __attribute__((ext_vector_type(8))) _Float16 f16x8;
typedef __attribute__((ext_vector_type(4))) _Float16 f16x4;
typedef __attribute__((ext_vector_type(4))) float f32x4;

constexpr int kT = 4096;    // B*L tokens
constexpr int kD = 1024;    // hidden
constexpr int kDW = 512;    // word embed proj dim
constexpr int kF = 4096;    // ffn
constexpr int kV = 50272;   // vocab

// Async global->LDS: HW places lane i's 16B at lds_base + i*16 (wave-uniform base).
__device__ __forceinline__ void gload16(const void* g, void* lbase, int lane) {
#if __has_builtin(__builtin_amdgcn_global_load_lds)
  __builtin_amdgcn_global_load_lds((const __attribute__((address_space(1))) void*)g,
                                   (__attribute__((address_space(3))) void*)lbase, 16, 0, 0);
#else
  *(f16x8*)((char*)lbase + lane * 16) = *(const f16x8*)g;
#endif
}

// ---------------------------------------------------------------------------
// gemm_p8 (proven best): 128x128 tile, 512 threads (8 waves), BK=64
// double-buffered LDS (64 KB -> 2 blocks/CU), counted vmcnt(4), row&7-XOR
// bank swizzle via pre-swizzled global source, XCD chunk swizzle.
// Split-K S. flags: bit0 relu (S==1), bit1 f32 out, bit2 f16 split partial
// ((f16*)Cv + s*M*ldc; bias on split 0 only).
// ---------------------------------------------------------------------------
__global__ __launch_bounds__(512, 4) void gemm_p8(
    const f16* __restrict__ A, const f16* __restrict__ W,
    const float* __restrict__ bias, void* __restrict__ Cv,
    int M, int N, int K, int ldc, int flags, int S)
{
  __shared__ f16 LA[2][128 * 64];
  __shared__ f16 LB[2][128 * 64];
  const int tid = threadIdx.x, lane = tid & 63, wv = tid >> 6;
  const int nby = M >> 7;
  const int nb = nby * (N >> 7);
  int id = blockIdx.x;
  id = (id & 7) * ((int)gridDim.x >> 3) + (id >> 3);   // XCD chunk swizzle
  const int s = id / nb;
  const int r = id - s * nb;
  const int bx = r / nby, by = r - bx * nby;
  const int row0 = by * 128, col0 = bx * 128;
  const int klen = K / S, koff = s * klen;
  const int wm = (wv >> 1) * 32, wn = (wv & 1) * 64;
  const int l15 = lane & 15, l4 = lane >> 4;

  f32x4 acc[2][4] = {};

  const int srow = wv * 16 + (lane >> 3);
  const int schunk = ((lane & 7) ^ (lane >> 3)) * 8;    // f16 units
  const f16* Ag = A + (size_t)(row0 + srow) * K + koff + schunk;
  const f16* Wg = W + (size_t)(col0 + srow) * K + koff + schunk;
  const int lrow = wv * 16;

  const int nt = klen >> 6;
#pragma unroll
  for (int j = 0; j < 2; ++j) {
    gload16(Ag + (size_t)j * 8 * K, &LA[0][(lrow + j * 8) * 64], lane);
    gload16(Wg + (size_t)j * 8 * K, &LB[0][(lrow + j * 8) * 64], lane);
  }

  for (int t = 0; t < nt; ++t) {
    const int cur = t & 1;
    if (t + 1 < nt) {
      const size_t ko = (size_t)(t + 1) * 64;
#pragma unroll
      for (int j = 0; j < 2; ++j) {
        gload16(Ag + (size_t)j * 8 * K + ko, &LA[cur ^ 1][(lrow + j * 8) * 64], lane);
        gload16(Wg + (size_t)j * 8 * K + ko, &LB[cur ^ 1][(lrow + j * 8) * 64], lane);
      }
      asm volatile("s_waitcnt vmcnt(4)" ::: "memory");   // stage(t) done; stage(t+1) in flight
    } else {
      asm volatile("s_waitcnt vmcnt(0)" ::: "memory");
    }
    __builtin_amdgcn_s_barrier();

    f16x8 af[2][2], bf[2][4];
#pragma unroll
    for (int ks = 0; ks < 2; ++ks) {
#pragma unroll
      for (int mr = 0; mr < 2; ++mr) {
        const int rowa = wm + mr * 16 + l15;
        af[ks][mr] = *(const f16x8*)&LA[cur][rowa * 64 + (((ks * 4 + l4) ^ (rowa & 7)) * 8)];
      }
#pragma unroll
      for (int nr = 0; nr < 4; ++nr) {
        const int rowb = wn + nr * 16 + l15;
        bf[ks][nr] = *(const f16x8*)&LB[cur][rowb * 64 + (((ks * 4 + l4) ^ (rowb & 7)) * 8)];
      }
    }
#pragma unroll
    for (int mr = 0; mr < 2; ++mr)
#pragma unroll
      for (int nr = 0; nr < 4; ++nr) {
        acc[mr][nr] = __builtin_amdgcn_mfma_f32_16x16x32_f16(af[0][mr], bf[0][nr], acc[mr][nr], 0, 0, 0);
        acc[mr][nr] = __builtin_amdgcn_mfma_f32_16x16x32_f16(af[1][mr], bf[1][nr], acc[mr][nr], 0, 0, 0);
      }
    __builtin_amdgcn_sched_barrier(0);
    __builtin_amdgcn_s_barrier();
  }

  const bool relu = (flags & 1) != 0;
  const bool outf = (flags & 2) != 0;
  const bool ph16 = (flags & 4) != 0;
  float* Cf = (float*)Cv + (size_t)s * M * ldc;
  f16* Cp = (f16*)Cv + (size_t)s * M * ldc;
  f16* Ch = (f16*)Cv;
  const float* bs = (s == 0) ? bias : nullptr;
#pragma unroll
  for (int nr = 0; nr < 4; ++nr) {
    const int col = col0 + wn + nr * 16 + l15;
    const float bv = bs ? bs[col] : 0.f;
#pragma unroll
    for (int mr = 0; mr < 2; ++mr) {
#pragma unroll
      for (int rr = 0; rr < 4; ++rr) {
        const int row = row0 + wm + mr * 16 + l4 * 4 + rr;
        float v = acc[mr][nr][rr] + bv;
        if (relu) v = fmaxf(v, 0.f);
        if (ph16)      Cp[(size_t)row * ldc + col] = (f16)v;
        else if (outf) Cf[(size_t)row * ldc + col] = v;
        else           Ch[(size_t)row * ldc + col] = (f16)v;
      }
    }
  }
}

// ---------------------------------------------------------------------------
// Fallback GEMM (W in f32, converted through regs) — round-0 proven kernel.
// ---------------------------------------------------------------------------
__global__ __launch_bounds__(256) void gemm_f16(
    const f16* __restrict__ A, const float* __restrict__ W,
    const float* __restrict__ bias, void* __restrict__ Cv,
    int M, int N, int K, int ldc, int flags)
{
  __shared__ f16 As[128][40];
  __shared__ f16 Ws[128][40];
  const int tid = threadIdx.x;
  const int lane = tid & 63;
  const int wid = tid >> 6;
  const int row0 = blockIdx.y * 128, col0 = blockIdx.x * 128;
  const int wm = (wid >> 1) * 64, wn = (wid & 1) * 64;
  const int l15 = lane & 15, k8 = (lane >> 4) * 8;
  const int lr = tid >> 2, lc8 = (tid & 3) * 8;

  f32x4 acc[4][4] = {};

  const f16* Ap = A + (size_t)(row0 + lr) * K + lc8;
  const float* Wp = W + (size_t)(col0 + lr) * K + lc8;

  for (int k0 = 0; k0 < K; k0 += 32) {
    f16x8 a0 = *(const f16x8*)(Ap + k0);
    f16x8 a1 = *(const f16x8*)(Ap + (size_t)64 * K + k0);
    f32x4 w00 = *(const f32x4*)(Wp + k0);
    f32x4 w01 = *(const f32x4*)(Wp + k0 + 4);
    f32x4 w10 = *(const f32x4*)(Wp + (size_t)64 * K + k0);
    f32x4 w11 = *(const f32x4*)(Wp + (size_t)64 * K + k0 + 4);
    f16x8 wv0, wv1;
#pragma unroll
    for (int j = 0; j < 4; ++j) {
      wv0[j] = (f16)w00[j]; wv0[4 + j] = (f16)w01[j];
      wv1[j] = (f16)w10[j]; wv1[4 + j] = (f16)w11[j];
    }
    __syncthreads();
    *(f16x8*)&As[lr][lc8] = a0;
    *(f16x8*)&As[lr + 64][lc8] = a1;
    *(f16x8*)&Ws[lr][lc8] = wv0;
    *(f16x8*)&Ws[lr + 64][lc8] = wv1;
    __syncthreads();
    f16x8 af[4], bfr[4];
#pragma unroll
    for (int r = 0; r < 4; ++r) af[r] = *(const f16x8*)&As[wm + r * 16 + l15][k8];
#pragma unroll
    for (int r = 0; r < 4; ++r) bfr[r] = *(const f16x8*)&Ws[wn + r * 16 + l15][k8];
#pragma unroll
    for (int mr = 0; mr < 4; ++mr)
#pragma unroll
      for (int nr = 0; nr < 4; ++nr)
        acc[mr][nr] = __builtin_amdgcn_mfma_f32_16x16x32_f16(af[mr], bfr[nr], acc[mr][nr], 0, 0, 0);
  }

  const bool relu = (flags & 1) != 0;
  const bool outf = (flags & 2) != 0;
  float* Cf = (float*)Cv;
  f16* Ch = (f16*)Cv;
#pragma unroll
  for (int nr = 0; nr < 4; ++nr) {
    const int col = col0 + wn + nr * 16 + l15;
    const float bv = bias ? bias[col] : 0.f;
#pragma unroll
    for (int mr = 0; mr < 4; ++mr) {
#pragma unroll
      for (int r = 0; r < 4; ++r) {
        const int row = row0 + wm + mr * 16 + (lane >> 4) * 4 + r;
        float v = acc[mr][nr][r] + bv;
        if (relu) v = fmaxf(v, 0.f);
        if (outf) Cf[(size_t)row * ldc + col] = v;
        else      Ch[(size_t)row * ldc + col] = (f16)v;
      }
    }
  }
}

// ---------------------------------------------------------------------------
// MFMA causal flash attention v4 + T5 setprio (neutral but harmless).
// Fixed-offset softmax P = exp2(S*0.125*log2e - 8*log2e); masked -> 0;
// lane-local l accumulation; K/V tile t+1 prefetched into registers.
// grid (L/128, H, B), 256 threads = 4 waves.
// ---------------------------------------------------------------------------
__global__ __launch_bounds__(256) void attn_mfma4(const f16* __restrict__ qkv,
                                                  f16* __restrict__ out)
{
  __shared__ f16 Ks[64][72];
  __shared__ f16 Vt[64][72];
  __shared__ f16 Ps[4][32][72];
  const int qt = blockIdx.x, h = blockIdx.y, b = blockIdx.z;
  const int tid = threadIdx.x, lane = tid & 63, wv = tid >> 6;
  const int l15 = lane & 15, l4 = lane >> 4;
  constexpr float kC1 = 0.18033688f;    // 0.125 * log2(e)
  constexpr float kC2 = -11.5415603f;   // -8 * log2(e)

  f16x8 qa[2][2];
#pragma unroll
  for (int mr = 0; mr < 2; ++mr) {
    const size_t qrow = (size_t)(b * 1024 + qt * 128 + wv * 32 + mr * 16 + l15);
#pragma unroll
    for (int ks = 0; ks < 2; ++ks)
      qa[mr][ks] = *(const f16x8*)(qkv + qrow * 3072 + h * 64 + ks * 32 + l4 * 8);
  }

  float l[2][4] = {};
  f32x4 o[2][4] = {};

  const int skey = tid >> 2;
  const int spart = (tid & 3) * 16;
  const int vxor = (skey >> 3) ^ (tid & 3);
  const int vcol = vxor * 8 + (skey & 7);
  const int qmin = qt * 128 + wv * 32;
  const int ntiles = 2 * qt + 2;

  f16x8 kk0, kk1, vv0, vv1;
  {
    const f16* kvb = qkv + (size_t)(b * 1024 + skey) * 3072 + h * 64;
    kk0 = *(const f16x8*)(kvb + 1024 + spart);
    kk1 = *(const f16x8*)(kvb + 1024 + spart + 8);
    vv0 = *(const f16x8*)(kvb + 2048 + spart);
    vv1 = *(const f16x8*)(kvb + 2048 + spart + 8);
  }

  for (int kt = 0; kt < ntiles; ++kt) {
    *(f16x8*)&Ks[skey][spart] = kk0;
    *(f16x8*)&Ks[skey][spart + 8] = kk1;
#pragma unroll
    for (int j = 0; j < 8; ++j) {
      Vt[spart + j][vcol] = vv0[j];
      Vt[spart + 8 + j][vcol] = vv1[j];
    }
    __syncthreads();
    if (kt + 1 < ntiles) {
      const f16* kvb = qkv + (size_t)(b * 1024 + (kt + 1) * 64 + skey) * 3072 + h * 64;
      kk0 = *(const f16x8*)(kvb + 1024 + spart);
      kk1 = *(const f16x8*)(kvb + 1024 + spart + 8);
      vv0 = *(const f16x8*)(kvb + 2048 + spart);
      vv1 = *(const f16x8*)(kvb + 2048 + spart + 8);
    }

    if (kt * 64 <= qmin + 31) {
      f32x4 s[2][4] = {};
      __builtin_amdgcn_s_setprio(1);
#pragma unroll
      for (int f = 0; f < 4; ++f) {
        f16x8 kb0 = *(const f16x8*)&Ks[f * 16 + l15][l4 * 8];
        f16x8 kb1 = *(const f16x8*)&Ks[f * 16 + l15][32 + l4 * 8];
#pragma unroll
        for (int mr = 0; mr < 2; ++mr) {
          s[mr][f] = __builtin_amdgcn_mfma_f32_16x16x32_f16(qa[mr][0], kb0, s[mr][f], 0, 0, 0);
          s[mr][f] = __builtin_amdgcn_mfma_f32_16x16x32_f16(qa[mr][1], kb1, s[mr][f], 0, 0, 0);
        }
      }
      __builtin_amdgcn_s_setprio(0);
#pragma unroll
      for (int mr = 0; mr < 2; ++mr) {
        float sc[4][4];
        const bool needmask = (kt * 64 + 63) > (qmin + mr * 16);
        if (needmask) {
#pragma unroll
          for (int f = 0; f < 4; ++f)
#pragma unroll
            for (int r = 0; r < 4; ++r) {
              const int qg = qmin + mr * 16 + l4 * 4 + r;
              const int kg = kt * 64 + f * 16 + l15;
              sc[f][r] = (kg <= qg) ? exp2f(fmaf(s[mr][f][r], kC1, kC2)) : 0.f;
            }
        } else {
#pragma unroll
          for (int f = 0; f < 4; ++f)
#pragma unroll
            for (int r = 0; r < 4; ++r)
              sc[f][r] = exp2f(fmaf(s[mr][f][r], kC1, kC2));
        }
#pragma unroll
        for (int r = 0; r < 4; ++r)
          l[mr][r] += (sc[0][r] + sc[1][r]) + (sc[2][r] + sc[3][r]);
#pragma unroll
        for (int f = 0; f < 4; ++f)
#pragma unroll
          for (int r = 0; r < 4; ++r)
            Ps[wv][mr * 16 + l4 * 4 + r][f * 16 + l15] = (f16)sc[f][r];
      }
      f16x8 pa[2][2];
#pragma unroll
      for (int mr = 0; mr < 2; ++mr)
#pragma unroll
        for (int ks = 0; ks < 2; ++ks)
          pa[mr][ks] = *(const f16x8*)&Ps[wv][mr * 16 + l15][ks * 32 + l4 * 8];
      __builtin_amdgcn_s_setprio(1);
#pragma unroll
      for (int hf = 0; hf < 4; ++hf) {
        f16x8 vb0 = *(const f16x8*)&Vt[hf * 16 + l15][((l4) ^ hf) * 8];
        f16x8 vb1 = *(const f16x8*)&Vt[hf * 16 + l15][((4 + l4) ^ hf) * 8];
#pragma unroll
        for (int mr = 0; mr < 2; ++mr) {
          o[mr][hf] = __builtin_amdgcn_mfma_f32_16x16x32_f16(pa[mr][0], vb0, o[mr][hf], 0, 0, 0);
          o[mr][hf] = __builtin_amdgcn_mfma_f32_16x16x32_f16(pa[mr][1], vb1, o[mr][hf], 0, 0, 0);
        }
      }
      __builtin_amdgcn_s_setprio(0);
    }
    __syncthreads();
  }

#pragma unroll
  for (int mr = 0; mr < 2; ++mr) {
    float inv[4];
#pragma unroll
    for (int r = 0; r < 4; ++r) {
      float L = l[mr][r];
      L += __shfl_xor(L, 1);
      L += __shfl_xor(L, 2);
      L += __shfl_xor(L, 4);
      L += __shfl_xor(L, 8);
      inv[r] = 1.f / L;
    }
    f16* dst = out + (size_t)(b * 1024 + qt * 128 + wv * 32 + mr * 16 + l4 * 4) * 1024 + h * 64 + l15;
#pragma unroll
    for (int hf = 0; hf < 4; ++hf)
#pragma unroll
      for (int r = 0; r < 4; ++r)
        dst[(size_t)r * 1024 + hf * 16] = (f16)(o[mr][hf][r] * inv[r]);
  }
}

// ---------------------------------------------------------------------------
// LayerNorm, pure-f16 residual stream: out_h = f16(LN(v) * w + b).
// ---------------------------------------------------------------------------
__device__ __forceinline__ void ln_body_h(f32x4 v, const float* w, const float* bvec,
                                          f16* Oh, size_t base, int tid)
{
  float sm = v[0] + v[1] + v[2] + v[3];
  float sq = v[0] * v[0] + v[1] * v[1] + v[2] * v[2] + v[3] * v[3];
#pragma unroll
  for (int msk = 32; msk; msk >>= 1) { sm += __shfl_xor(sm, msk); sq += __shfl_xor(sq, msk); }
  __shared__ float sb[4], qb_[4];
  const int wid = tid >> 6, lane = tid & 63;
  if (lane == 0) { sb[wid] = sm; qb_[wid] = sq; }
  __syncthreads();
  sm = sb[0] + sb[1] + sb[2] + sb[3];
  sq = qb_[0] + qb_[1] + qb_[2] + qb_[3];
  const float mean = sm * (1.f / 1024.f);
  const float var = sq * (1.f / 1024.f) - mean * mean;
  const float rstd = rsqrtf(var + 1e-5f);
  const f32x4 w4 = *(const f32x4*)&w[tid * 4];
  const f32x4 b4 = *(const f32x4*)&bvec[tid * 4];
  f16x4 yh;
#pragma unroll
  for (int j = 0; j < 4; ++j)
    yh[j] = (f16)((v[j] - mean) * rstd * w4[j] + b4[j]);
  *(f16x4*)&Oh[base] = yh;
}

// out_h = LN(R_h + X1h + X2h); in-place safe (one row per block).
__global__ __launch_bounds__(256) void add_lnh(
    const f16* __restrict__ R, const f16* __restrict__ X1,
    const f16* __restrict__ X2,
    const float* __restrict__ w, const float* __restrict__ bvec,
    f16* __restrict__ Oh)
{
  const int row = blockIdx.x, tid = threadIdx.x;
  const size_t base = (size_t)row * 1024 + tid * 4;
  const f16x4 r4 = *(const f16x4*)&R[base];
  const f16x4 x1 = *(const f16x4*)&X1[base];
  const f16x4 x2 = *(const f16x4*)&X2[base];
  f32x4 v;
#pragma unroll
  for (int j = 0; j < 4; ++j) v[j] = (float)r4[j] + (float)x1[j] + (float)x2[j];
  ln_body_h(v, w, bvec, Oh, base, tid);
}

// legacy 2-input f32 version (fallback path)
__global__ __launch_bounds__(256) void add_ln(
    const float* __restrict__ R, const float* __restrict__ X,
    const float* __restrict__ w, const float* __restrict__ bvec,
    float* __restrict__ O32, f16* __restrict__ Oh)
{
  const int row = blockIdx.x, tid = threadIdx.x;
  const size_t base = (size_t)row * 1024 + tid * 4;
  f32x4 v = *(const f32x4*)&R[base];
  v += *(const f32x4*)&X[base];
  float sm = v[0] + v[1] + v[2] + v[3];
  float sq = v[0] * v[0] + v[1] * v[1] + v[2] * v[2] + v[3] * v[3];
#pragma unroll
  for (int msk = 32; msk; msk >>= 1) { sm += __shfl_xor(sm, msk); sq += __shfl_xor(sq, msk); }
  __shared__ float sb[4], qb_[4];
  const int wid = tid >> 6, lane = tid & 63;
  if (lane == 0) { sb[wid] = sm; qb_[wid] = sq; }
  __syncthreads();
  sm = sb[0] + sb[1] + sb[2] + sb[3];
  sq = qb_[0] + qb_[1] + qb_[2] + qb_[3];
  const float mean = sm * (1.f / 1024.f);
  const float var = sq * (1.f / 1024.f) - mean * mean;
  const float rstd = rsqrtf(var + 1e-5f);
  const f32x4 w4 = *(const f32x4*)&w[tid * 4];
  const f32x4 b4 = *(const f32x4*)&bvec[tid * 4];
  f32x4 y;
  f16x4 yh;
#pragma unroll
  for (int j = 0; j < 4; ++j) {
    y[j] = (v[j] - mean) * rstd * w4[j] + b4[j];
    yh[j] = (f16)y[j];
  }
  *(f32x4*)&O32[base] = y;
  *(f16x4*)&Oh[base] = yh;
}

// E[t, :] = f16(embed_w[ids[t], :])   (fallback path)
__global__ __launch_bounds__(256) void gather_embed(
    const int* __restrict__ ids, const float* __restrict__ ew, f16* __restrict__ E)
{
  const int idx = blockIdx.x * 256 + threadIdx.x;
  const int t = idx >> 6, c = (idx & 63) * 8;
  const float* src = ew + (size_t)ids[t] * 512 + c;
  f32x4 f0 = *(const f32x4*)src, f1 = *(const f32x4*)(src + 4);
  f16x8 o_;
#pragma unroll
  for (int j = 0; j < 4; ++j) { o_[j] = (f16)f0[j]; o_[4 + j] = (f16)f1[j]; }
  *(f16x8*)(E + (size_t)t * 512 + c) = o_;
}

// Hh = f16(X1h + X2h + pos_w[positions[t]+2])
__global__ __launch_bounds__(256) void pos_addh(
    const f16* __restrict__ X1, const f16* __restrict__ X2,
    const float* __restrict__ posw,
    const int* __restrict__ positions, f16* __restrict__ Hh)
{
  const int idx = blockIdx.x * 256 + threadIdx.x;
  const int t = idx >> 7, c = (idx & 127) * 8;
  const size_t base = (size_t)t * 1024 + c;
  const float* pp = posw + (size_t)(positions[t] + 2) * 1024 + c;
  const f16x8 x1 = *(const f16x8*)&X1[base];
  const f16x8 x2 = *(const f16x8*)&X2[base];
  f32x4 a0 = *(const f32x4*)pp;
  f32x4 a1 = *(const f32x4*)(pp + 4);
  f16x8 hh;
#pragma unroll
  for (int j = 0; j < 4; ++j) {
    hh[j]     = (f16)(a0[j] + (float)x1[j] + (float)x2[j]);
    hh[4 + j] = (f16)(a1[j] + (float)x1[4 + j] + (float)x2[4 + j]);
  }
  *(f16x8*)&Hh[base] = hh;
}

// legacy single-input version (fallback path)
__global__ __launch_bounds__(256) void pos_add(
    const float* __restrict__ X, const float* __restrict__ posw,
    const int* __restrict__ positions, float* __restrict__ H32, f16* __restrict__ Hh)
{
  const int idx = blockIdx.x * 256 + threadIdx.x;
  const int t = idx >> 7, c = (idx & 127) * 8;
  const float* xp = X + (size_t)t * 1024 + c;
  const float* pp = posw + (size_t)(positions[t] + 2) * 1024 + c;
  f32x4 a0 = *(const f32x4*)xp, a1 = *(const f32x4*)(xp + 4);
  a0 += *(const f32x4*)pp;
  a1 += *(const f32x4*)(pp + 4);
  f16x8 hh;
#pragma unroll
  for (int j = 0; j < 4; ++j) { hh[j] = (f16)a0[j]; hh[4 + j] = (f16)a1[j]; }
  *(f32x4*)&H32[(size_t)t * 1024 + c] = a0;
  *(f32x4*)&H32[(size_t)t * 1024 + c + 4] = a1;
  *(f16x8*)&Hh[(size_t)t * 1024 + c] = hh;
}

// y[b, w] = hbf[offsets[b]-1, :] . proj_out_w[w, :]   (one wave per output)
__global__ __launch_bounds__(256) void last_projh(
    const f16* __restrict__ Hh, const float* __restrict__ pw,
    const int* __restrict__ offs, float* __restrict__ y)
{
  const int o = blockIdx.x * 4 + (threadIdx.x >> 6), lane = threadIdx.x & 63;
  const int b = o >> 9, w = o & 511;
  const int row = offs[b] - 1;
  const f16* hp = Hh + (size_t)row * 1024 + lane * 16;
  const float* wp = pw + (size_t)w * 1024 + lane * 16;
  const f16x8 h0 = *(const f16x8*)hp;
  const f16x8 h1 = *(const f16x8*)(hp + 8);
  float s = 0.f;
#pragma unroll
  for (int j = 0; j < 8; ++j) {
    s += (float)h0[j] * wp[j];
    s += (float)h1[j] * wp[8 + j];
  }
#pragma unroll
  for (int msk = 32; msk; msk >>= 1) s += __shfl_xor(s, msk);
  if (lane == 0) y[o] = s;
}

// legacy f32 version (fallback path)
__global__ __launch_bounds__(256) void last_proj(
    const float* __restrict__ H32, const float* __restrict__ pw,
    const int* __restrict__ offs, float* __restrict__ y)
{
  const int o = blockIdx.x * 4 + (threadIdx.x >> 6), lane = threadIdx.x & 63;
  const int b = o >> 9, w = o & 511;
  const int row = offs[b] - 1;
  const float* hp = H32 + (size_t)row * 1024;
  const float* wp = pw + (size_t)w * 1024;
  float s = 0.f;
#pragma unroll
  for (int j = 0; j < 4; ++j) {
    f32x4 hv = *(const f32x4*)&hp[(lane + 64 * j) * 4];
    f32x4 wv = *(const f32x4*)&wp[(lane + 64 * j) * 4];
    s += hv[0] * wv[0] + hv[1] * wv[1] + hv[2] * wv[2] + hv[3] * wv[3];
  }
#pragma unroll
  for (int msk = 32; msk; msk >>= 1) s += __shfl_xor(s, msk);
  if (lane == 0) y[o] = s;
}

// logits: each block = 4 vocab rows x all 4 batches (embed read once).
__global__ __launch_bounds__(256) void logits4(const float* __restrict__ y,
                                               const float* __restrict__ ew,
                                               float* __restrict__ out)
{
  __shared__ float ys[2048];
  const int tid = threadIdx.x;
  ((f32x4*)ys)[tid] = ((const f32x4*)y)[tid];
  ((f32x4*)ys)[tid + 256] = ((const f32x4*)y)[tid + 256];
  __syncthreads();
  const int v = blockIdx.x * 4 + (tid >> 6);
  const int lane = tid & 63;
  const float* wp = ew + (size_t)v * 512 + lane * 8;
  const f32x4 e0 = *(const f32x4*)wp;
  const f32x4 e1 = *(const f32x4*)(wp + 4);
  float s0 = 0.f, s1 = 0.f, s2 = 0.f, s3 = 0.f;
#pragma unroll
  for (int j = 0; j < 4; ++j) {
    const int c0 = lane * 8 + j, c1 = lane * 8 + 4 + j;
    s0 += e0[j] * ys[c0] + e1[j] * ys[c1];
    s1 += e0[j] * ys[512 + c0] + e1[j] * ys[512 + c1];
    s2 += e0[j] * ys[1024 + c0] + e1[j] * ys[1024 + c1];
    s3 += e0[j] * ys[1536 + c0] + e1[j] * ys[1536 + c1];
  }
#pragma unroll
  for (int msk = 32; msk; msk >>= 1) {
    s0 += __shfl_xor(s0, msk); s1 += __shfl_xor(s1, msk);
    s2 += __shfl_xor(s2, msk); s3 += __shfl_xor(s3, msk);
  }
  if (lane == 0) {
    out[v] = s0;
    out[50272 + v] = s1;
    out[2 * 50272 + v] = s2;
    out[3 * 50272 + v] = s3;
  }
}

// ---------------------------------------------------------------------------
// pack_all (r20 proven, 88 us): single-launch prep, one-shot flat index
// space (A/B r21: grid-stride at 2048 blocks was SLOWER, 96 us — block
// launch overhead negligible, stride loop overhead real).
// Segments (f16x8 work items unless noted):
//   [0,          65536)   proj_in_w  -> pw_in
//   [65536,    1638400)   q|k|v pack -> qkvw
//   [1638400,  2162688)   ow         -> oww
//   [2162688,  4259840)   fc1w       -> f1w
//   [4259840,  6356992)   fc2w       -> f2w
//   [6356992,  6619136)   embed gather -> E   (T*64 = 262144 items)
//   [6619136,  6631424)   qkv bias scalars -> qkvb (1 f32/item)
// total = 6631424 = 25904 blocks x 256.
// ---------------------------------------------------------------------------
__global__ __launch_bounds__(256) void pack_all(
    const float* __restrict__ proj_in_w, f16* __restrict__ pw_in,
    const float* __restrict__ qw, const float* __restrict__ kw,
    const float* __restrict__ vw, f16* __restrict__ qkvw,
    const float* __restrict__ ow, f16* __restrict__ oww,
    const float* __restrict__ fc1w, f16* __restrict__ f1w,
    const float* __restrict__ fc2w, f16* __restrict__ f2w,
    const int* __restrict__ ids, const float* __restrict__ ew, f16* __restrict__ E,
    const float* __restrict__ qb, const float* __restrict__ kb,
    const float* __restrict__ vb, float* __restrict__ qkvb)
{
  const int idx = blockIdx.x * 256 + threadIdx.x;
  if (idx >= 6631424) return;

  const float* src = nullptr;
  f16* dst = nullptr;
  if (idx < 65536) {
    src = proj_in_w + (size_t)idx * 8;
    dst = pw_in + (size_t)idx * 8;
  } else if (idx < 1638400) {
    const size_t e = (size_t)(idx - 65536) * 8;
    const size_t li = e / 3145728;
    const size_t r = e - li * 3145728;
    const int mt = (int)(r >> 20);
    const size_t c = r & 1048575;
    src = (mt == 0 ? qw : (mt == 1 ? kw : vw)) + li * 1048576 + c;
    dst = qkvw + e;
  } else if (idx < 2162688) {
    const size_t e = (size_t)(idx - 1638400) * 8;
    src = ow + e;
    dst = oww + e;
  } else if (idx < 4259840) {
    const size_t e = (size_t)(idx - 2162688) * 8;
    src = fc1w + e;
    dst = f1w + e;
  } else if (idx < 6356992) {
    const size_t e = (size_t)(idx - 4259840) * 8;
    src = fc2w + e;
    dst = f2w + e;
  } else if (idx < 6619136) {
    const int j = idx - 6356992;                 // T*64 gather units
    const int t = j >> 6, c = (j & 63) * 8;
    src = ew + (size_t)ids[t] * 512 + c;
    dst = E + (size_t)t * 512 + c;
  } else {
    const int i = idx - 6619136;                 // qkv bias scalar
    const int li = i / 3072;
    const int r = i - li * 3072;
    const int mt = r >> 10;
    const int c = r & 1023;
    const float* s = (mt == 0 ? qb : (mt == 1 ? kb : vb));
    qkvb[i] = s[li * 1024 + c];
    return;
  }
  const f32x4 a = *(const f32x4*)src;
  const f32x4 b = *(const f32x4*)(src + 4);
  f16x8 o_;
#pragma unroll
  for (int j = 0; j < 4; ++j) { o_[j] = (f16)a[j]; o_[4 + j] = (f16)b[j]; }
  *(f16x8*)dst = o_;
}

// ---------------------------------------------------------------------------
extern "C" void kernel_launch(void* const* d_in, const int* in_sizes, int n_in,
                              void* d_out, int out_size, void* d_ws, size_t ws_size,
                              hipStream_t stream)
{
  const int* ids        = (const int*)d_in[0];
  const int* positions  = (const int*)d_in[1];
  const int* offs       = (const int*)d_in[2];
  const float* embed_w    = (const float*)d_in[6];
  const float* pos_w      = (const float*)d_in[7];
  const float* proj_in_w  = (const float*)d_in[8];
  const float* proj_out_w = (const float*)d_in[9];
  const float* ln1w = (const float*)d_in[10];
  const float* ln1b = (const float*)d_in[11];
  const float* qw   = (const float*)d_in[12];
  const float* qb   = (const float*)d_in[13];
  const float* kw   = (const float*)d_in[14];
  const float* kb   = (const float*)d_in[15];
  const float* vw   = (const float*)d_in[16];
  const float* vb   = (const float*)d_in[17];
  const float* ow   = (const float*)d_in[18];
  const float* ob   = (const float*)d_in[19];
  const float* fc1w = (const float*)d_in[20];
  const float* fc1b = (const float*)d_in[21];
  const float* fc2w = (const float*)d_in[22];
  const float* fc2b = (const float*)d_in[23];
  const float* ln2w = (const float*)d_in[24];
  const float* ln2b = (const float*)d_in[25];

  char* ws = (char*)d_ws;
  size_t off = 0;
  auto take = [&](size_t bytes) -> char* {
    char* p = ws + off;
    off += (bytes + 255) & ~(size_t)255;
    return p;
  };
  f16*   E   = (f16*)  take((size_t)kT * kDW * 2);
  float* h32 = (float*)take((size_t)kT * kD * 4);      // fallback path only
  f16*   hbf = (f16*)  take((size_t)kT * kD * 2);      // f16 residual stream
  f16*   qkv = (f16*)  take((size_t)kT * 3072 * 2);
  f16*   att = (f16*)  take((size_t)kT * kD * 2);
  f16*   t1  = (f16*)  take((size_t)kT * kF * 2);
  float* t2  = (float*)take((size_t)kT * kD * 4 * 2);  // region reused for f16 partials
  float* yb  = (float*)take((size_t)4 * kDW * 4);
  f16*   pw_in = (f16*)take((size_t)kD * kDW * 2);
  f16*   qkvw  = (f16*)take((size_t)4 * 3072 * kD * 2);
  f16*   oww   = (f16*)take((size_t)4 * kD * kD * 2);
  f16*   f1w   = (f16*)take((size_t)4 * kF * kD * 2);
  f16*   f2w   = (f16*)take((size_t)4 * kD * kF * 2);
  float* qkvb  = (float*)take((size_t)4 * 3072 * 4);
  const bool wok = (off <= ws_size);
  f16* tp  = (f16*)t2;                       // split partial 0 (f16)
  f16* tpb = tp + (size_t)kT * kD;           // split partial 1 (f16)
  (void)in_sizes; (void)n_in; (void)out_size;

  const dim3 blk(256);
  const dim3 blk8(512);
  const dim3 gD(kD / 128, kT / 128);
  const dim3 gF(kF / 128, kT / 128);
  const dim3 gAtt(8, 16, 4);         // 128-row q tiles
  const int nbD   = (kD / 128) * (kT / 128);     // 256
  const int nbQKV = (3072 / 128) * (kT / 128);   // 768
  const int nbF   = (kF / 128) * (kT / 128);     // 1024

  if (wok) {
    pack_all<<<25904, blk, 0, stream>>>(proj_in_w, pw_in, qw, kw, vw, qkvw,
                                        ow, oww, fc1w, f1w, fc2w, f2w,
                                        ids, embed_w, E, qb, kb, vb, qkvb);
  } else {
    gather_embed<<<1024, blk, 0, stream>>>(ids, embed_w, E);
  }

  if (wok) {
    gemm_p8<<<nbD * 2, blk8, 0, stream>>>(E, pw_in, nullptr, tp, kT, kD, kDW, kD, 4, 2);
    pos_addh<<<2048, blk, 0, stream>>>(tp, tpb, pos_w, positions, hbf);
  } else {
    gemm_f16<<<gD, blk, 0, stream>>>(E, proj_in_w, nullptr, t2, kT, kD, kDW, kD, 2);
    pos_add<<<2048, blk, 0, stream>>>(t2, pos_w, positions, h32, hbf);
  }

  for (int n = 0; n < 4; ++n) {
    const size_t wo = (size_t)n * kD * kD;
    if (wok) {
      gemm_p8<<<nbQKV, blk8, 0, stream>>>(hbf, qkvw + (size_t)n * 3145728, qkvb + n * 3072,
                                          qkv, kT, 3072, kD, 3072, 0, 1);
      attn_mfma4<<<gAtt, blk, 0, stream>>>(qkv, att);
      gemm_p8<<<nbD * 2, blk8, 0, stream>>>(att, oww + wo, ob + n * kD, tp, kT, kD, kD, kD, 4, 2);
      add_lnh<<<kT, blk, 0, stream>>>(hbf, tp, tpb, ln1w + n * kD, ln1b + n * kD, hbf);
      gemm_p8<<<nbF, blk8, 0, stream>>>(hbf, f1w + (size_t)n * kF * kD, fc1b + n * kF, t1, kT, kF, kD, kF, 1, 1);
      gemm_p8<<<nbD * 2, blk8, 0, stream>>>(t1, f2w + (size_t)n * kD * kF, fc2b + n * kD, tp, kT, kD, kF, kD, 4, 2);
      add_lnh<<<kT, blk, 0, stream>>>(hbf, tp, tpb, ln2w + n * kD, ln2b + n * kD, hbf);
    } else {
      gemm_f16<<<gD, blk, 0, stream>>>(hbf, qw + wo, qb + n * kD, qkv + 0,    kT, kD, kD, 3072, 0);
      gemm_f16<<<gD, blk, 0, stream>>>(hbf, kw + wo, kb + n * kD, qkv + 1024, kT, kD, kD, 3072, 0);
      gemm_f16<<<gD, blk, 0, stream>>>(hbf, vw + wo, vb + n * kD, qkv + 2048, kT, kD, kD, 3072, 0);
      attn_mfma4<<<gAtt, blk, 0, stream>>>(qkv, att);
      gemm_f16<<<gD, blk, 0, stream>>>(att, ow + wo, ob + n * kD, t2, kT, kD, kD, kD, 2);
      add_ln<<<kT, blk, 0, stream>>>(h32, t2, ln1w + n * kD, ln1b + n * kD, h32, hbf);
      gemm_f16<<<gF, blk, 0, stream>>>(hbf, fc1w + (size_t)n * kF * kD, fc1b + n * kF, t1, kT, kF, kD, kF, 1);
      gemm_f16<<<gD, blk, 0, stream>>>(t1, fc2w + (size_t)n * kD * kF, fc2b + n * kD, t2, kT, kD, kF, kD, 2);
      add_ln<<<kT, blk, 0, stream>>>(h32, t2, ln2w + n * kD, ln2b + n * kD, h32, hbf);
    }
  }

  if (wok) last_projh<<<512, blk, 0, stream>>>(hbf, proj_out_w, offs, yb);
  else     last_proj<<<512, blk, 0, stream>>>(h32, proj_out_w, offs, yb);
  logits4<<<12568, blk, 0, stream>>>(yb, embed_w, (float*)d_out);
}